// Round 1
// 453.777 us; speedup vs baseline: 1.0019x; 1.0019x over previous
//
#include <hip/hip_runtime.h>

// Fully-fused undecimated starlet analysis, 4 scales, separable [1,4,6,4,1]/16,
// dilation 2^s, symmetric boundary. ONE kernel: stage 124^2 region (tile 64 +
// cumulative halo 30 per side) into LDS, then per scale: horizontal dilated
// 5-tap (A->B), stash central low (A->S), vertical 5-tap + coeff store
// (B,S -> A in-place + global). Intermediate lows never touch HBM.
//
// Mirror-once correctness: symmetric filter * mirror extension == mirror
// extension of filtered interior, so staging the mirrored ORIGINAL image is
// exactly equivalent to the reference's per-scale symmetric pad.

#define IMG    1024
#define NBATCH 16
#define TILE   64
#define RTOT   30                 // 2*(1+2+4+8) cumulative halo
#define SA     (TILE + 2 * RTOT)  // 124: staged side == A stride
#define BS     1024

static_assert(SA == 124, "halo arithmetic");

__device__ __forceinline__ int mirror_idx(int g, int n) {
    // jnp.pad mode='symmetric': -1 -> 0, -2 -> 1, n -> n-1 (single fold is
    // sufficient: |offset| <= 30 << 1024)
    g = (g < 0) ? (-1 - g) : g;
    g = (g >= n) ? (2 * n - 1 - g) : g;
    return g;
}

__device__ __forceinline__ float4 tap5(float4 q0, float4 q1, float4 q2,
                                       float4 q3, float4 q4) {
    float4 o;
    o.x = 0.375f * q2.x + 0.25f * (q1.x + q3.x) + 0.0625f * (q0.x + q4.x);
    o.y = 0.375f * q2.y + 0.25f * (q1.y + q3.y) + 0.0625f * (q0.y + q4.y);
    o.z = 0.375f * q2.z + 0.25f * (q1.z + q3.z) + 0.0625f * (q0.z + q4.z);
    o.w = 0.375f * q2.w + 0.25f * (q1.w + q3.w) + 0.0625f * (q0.w + q4.w);
    return o;
}

// Horizontal dilated 5-tap: A (stride SA, NIN x NIN) -> B (stride NOUT, NIN x NOUT).
// Each thread computes 4 consecutive outputs; taps gathered as aligned float4s.
template <int D, int NIN>
__device__ __forceinline__ void h_pass(const float* __restrict__ A,
                                       float* __restrict__ B, int tid) {
    constexpr int NOUT = NIN - 4 * D;
    constexpr int GX = NOUT / 4;
    for (int t = tid; t < NIN * GX; t += BS) {
        const int y = t / GX;
        const int x = (t - y * GX) * 4;
        const float* row = &A[y * SA + x];
        float4 o;
        if constexpr (D == 1) {
            const float4 a = *(const float4*)(row);
            const float4 b = *(const float4*)(row + 4);
            o = tap5(a,
                     make_float4(a.y, a.z, a.w, b.x),
                     make_float4(a.z, a.w, b.x, b.y),
                     make_float4(a.w, b.x, b.y, b.z),
                     b);
        } else if constexpr (D == 2) {
            const float4 a = *(const float4*)(row);
            const float4 b = *(const float4*)(row + 4);
            const float4 c = *(const float4*)(row + 8);
            o = tap5(a,
                     make_float4(a.z, a.w, b.x, b.y),
                     b,
                     make_float4(b.z, b.w, c.x, c.y),
                     c);
        } else {  // D multiple of 4: every tap quad is 16B-aligned
            o = tap5(*(const float4*)(row),
                     *(const float4*)(row + D),
                     *(const float4*)(row + 2 * D),
                     *(const float4*)(row + 3 * D),
                     *(const float4*)(row + 4 * D));
        }
        *(float4*)(&B[y * NOUT + x]) = o;
    }
}

// Stash central 64^2 of low_s before v_pass overwrites A.
template <int NIN>
__device__ __forceinline__ void copy_central(const float* __restrict__ A,
                                             float* __restrict__ S, int tid) {
    constexpr int PMIN = (NIN - TILE) / 2;  // == 30 - O_s (centered layout)
    for (int t = tid; t < TILE * TILE; t += BS) {
        const int sy = t >> 6;
        const int sx = t & (TILE - 1);
        S[t] = A[(PMIN + sy) * SA + (PMIN + sx)];
    }
}

// Vertical dilated 5-tap: B -> new low (A, in-place, stride SA) + central
// coeff = (S - new_low) * inv  ->  global (float4 stores, all aligned).
template <int D, int NIN, bool LAST>
__device__ __forceinline__ void v_pass(float* __restrict__ A,
                                       const float* __restrict__ B,
                                       const float* __restrict__ S,
                                       float* __restrict__ gout, size_t img_off,
                                       int ty0, int tx0, float inv, int tid) {
    constexpr int NOUT = NIN - 4 * D;
    constexpr int GX = NOUT / 4;
    constexpr int CMIN = (NOUT - TILE) / 2;  // central window offset
    for (int t = tid; t < NOUT * GX; t += BS) {
        const int y = t / GX;
        const int x = (t - y * GX) * 4;
        const float* col = &B[y * NOUT + x];
        const float4 nl = tap5(*(const float4*)(col),
                               *(const float4*)(col + D * NOUT),
                               *(const float4*)(col + 2 * D * NOUT),
                               *(const float4*)(col + 3 * D * NOUT),
                               *(const float4*)(col + 4 * D * NOUT));
        if constexpr (!LAST) {
            *(float4*)(&A[y * SA + x]) = nl;  // low_{s+1}, region-local at (0,0)
        }
        if (y >= CMIN && y < CMIN + TILE && x >= CMIN && x < CMIN + TILE) {
            const int sy = y - CMIN, sx = x - CMIN;
            const float4 lo = *(const float4*)(&S[sy * TILE + sx]);
            float4 cf;
            cf.x = (lo.x - nl.x) * inv;
            cf.y = (lo.y - nl.y) * inv;
            cf.z = (lo.z - nl.z) * inv;
            cf.w = (lo.w - nl.w) * inv;
            *(float4*)(&gout[img_off + (size_t)(ty0 + sy) * IMG + (tx0 + sx)]) = cf;
        }
    }
}

__global__ __launch_bounds__(BS)
void starlet_fused(const float* __restrict__ img, const float* __restrict__ norms,
                   float* __restrict__ out)
{
    __shared__ float A[SA * SA];        // 61.5 KB: staged image / running low
    __shared__ float B[SA * (SA - 4)];  // 59.5 KB: horizontal-pass tmp (max 124x120)
    __shared__ float S[TILE * TILE];    // 16 KB: central low_s for the subtract
    // total 137.4 KB LDS -> 1 block/CU, 16 waves resident

    const int tid = threadIdx.x;
    const int tx0 = blockIdx.x * TILE;
    const int ty0 = blockIdx.y * TILE;
    const size_t img_off = (size_t)blockIdx.z * (size_t)(IMG * IMG);
    const size_t plane = (size_t)NBATCH * IMG * IMG;

    const float i0 = 1.0f / norms[0];
    const float i1 = 1.0f / norms[1];
    const float i2 = 1.0f / norms[2];
    const float i3 = 1.0f / norms[3];

    // ---- stage 124^2 region with symmetric mirroring (coalesced in rx) ----
    for (int i = tid; i < SA * SA; i += BS) {
        const int ry = i / SA;
        const int rx = i - ry * SA;
        const int gy = mirror_idx(ty0 - RTOT + ry, IMG);
        const int gx = mirror_idx(tx0 - RTOT + rx, IMG);
        A[i] = img[img_off + (size_t)gy * IMG + gx];
    }
    __syncthreads();

    // ---- scale 0: D=1, 124 -> 120 ----
    h_pass<1, 124>(A, B, tid);
    copy_central<124>(A, S, tid);
    __syncthreads();
    v_pass<1, 124, false>(A, B, S, out, img_off, ty0, tx0, i0, tid);
    __syncthreads();

    // ---- scale 1: D=2, 120 -> 112 ----
    h_pass<2, 120>(A, B, tid);
    copy_central<120>(A, S, tid);
    __syncthreads();
    v_pass<2, 120, false>(A, B, S, out + plane, img_off, ty0, tx0, i1, tid);
    __syncthreads();

    // ---- scale 2: D=4, 112 -> 96 ----
    h_pass<4, 112>(A, B, tid);
    copy_central<112>(A, S, tid);
    __syncthreads();
    v_pass<4, 112, false>(A, B, S, out + 2 * plane, img_off, ty0, tx0, i2, tid);
    __syncthreads();

    // ---- scale 3: D=8, 96 -> 64 (low4 discarded) ----
    h_pass<8, 96>(A, B, tid);
    copy_central<96>(A, S, tid);
    __syncthreads();
    v_pass<8, 96, true>(A, B, S, out + 3 * plane, img_off, ty0, tx0, i3, tid);
}

extern "C" void kernel_launch(void* const* d_in, const int* in_sizes, int n_in,
                              void* d_out, int out_size, void* d_ws, size_t ws_size,
                              hipStream_t stream) {
    const float* image = (const float*)d_in[0];
    const float* norms = (const float*)d_in[1];
    float* out = (float*)d_out;

    dim3 grid(IMG / TILE, IMG / TILE, NBATCH);
    starlet_fused<<<grid, dim3(BS), 0, stream>>>(image, norms, out);
}